// Round 5
// baseline (565.470 us; speedup 1.0000x reference)
//
#include <hip/hip_runtime.h>
#include <hip/hip_bf16.h>
#include <stdint.h>

#define T_TOK 2048
#define IDIM  1024
#define HID   4096
#define NE    8
#define BM    128
#define BN    128
#define BK    64
#define RMAX  5120
#define MAXTILES 40

typedef __bf16 bf16;
typedef bf16  bf16x8 __attribute__((ext_vector_type(8)));
typedef float f32x4  __attribute__((ext_vector_type(4)));

// ---- workspace layout (byte offsets) ----
#define WS_COUNTS   0        // 8 int
#define WS_CURSOR   64       // 8 int
#define WS_NTILES   128      // 1 int
#define WS_TILE_E   192      // 64 int
#define WS_TILE_R   448      // 64 int
#define WS_TOK_E    1024     // 2*T int
#define WS_TOK_W    17408    // 2*T float
#define WS_ROW_TOK  33792    // RMAX int (-1 = pad)
#define WS_ROW_W    54272    // RMAX float
#define WS_H        131072   // RMAX * (HID/HC) bf16
#define WS_MIN_FAST ((size_t)WS_H + (size_t)RMAX * (HID / 32) * 2)  // ~1.44 MB

// ---------------- zeroing (graph-capture-safe) ----------------
__global__ void k_zero_meta(int* __restrict__ w) {
    if (threadIdx.x < 48) w[threadIdx.x] = 0;
}
__global__ __launch_bounds__(256) void k_zero_out(float4* __restrict__ a) {
    a[blockIdx.x * 256 + threadIdx.x] = make_float4(0.f, 0.f, 0.f, 0.f);
}

// ---------------- router: one wave per token (pure fp32) ----------------
__global__ __launch_bounds__(256) void k_router(const float* __restrict__ xs,
                                                const float* __restrict__ Wg,
                                                int* __restrict__ counts,
                                                int* __restrict__ tok_e,
                                                float* __restrict__ tok_w) {
    __shared__ float sWg[NE * IDIM];
    for (int i = threadIdx.x; i < NE * IDIM; i += 256) sWg[i] = Wg[i];
    __syncthreads();
    int wave = threadIdx.x >> 6, lane = threadIdx.x & 63;
    int t = blockIdx.x * 4 + wave;
    if (t >= T_TOK) return;
    float p[NE];
#pragma unroll
    for (int e = 0; e < NE; e++) p[e] = 0.f;
    for (int j = 0; j < IDIM / 64; j++) {
        float x = xs[(size_t)t * IDIM + j * 64 + lane];
#pragma unroll
        for (int e = 0; e < NE; e++)
            p[e] += x * sWg[e * IDIM + j * 64 + lane];
    }
#pragma unroll
    for (int e = 0; e < NE; e++) {
        float v = p[e];
        for (int off = 32; off > 0; off >>= 1) v += __shfl_down(v, off);
        p[e] = v;
    }
    if (lane == 0) {
        int e0 = 0; float l0 = p[0];
        for (int e = 1; e < NE; e++) if (p[e] > l0) { l0 = p[e]; e0 = e; }
        int e1 = -1; float l1 = -1e30f;
        for (int e = 0; e < NE; e++) if (e != e0 && p[e] > l1) { l1 = p[e]; e1 = e; }
        if (e1 < 0) e1 = (e0 + 1) & 7;          // safety: never index -1
        float z = __expf(l1 - l0);              // <= 1
        float w0 = 1.f / (1.f + z);
        float w1 = z / (1.f + z);                // weights stay fp32 (ref)
        tok_e[2 * t]     = e0;  tok_e[2 * t + 1] = e1;
        tok_w[2 * t]     = w0;  tok_w[2 * t + 1] = w1;
        atomicAdd(&counts[e0], 1);
        atomicAdd(&counts[e1], 1);
    }
}

// ---------------- plan ----------------
__global__ void k_plan(int* __restrict__ w) {
    if (threadIdx.x == 0) {
        int off = 0, nt = 0;
        for (int e = 0; e < NE; e++) {
            w[WS_CURSOR / 4 + e] = off;
            int c  = w[WS_COUNTS / 4 + e];
            int nb = (c + BM - 1) / BM;
            for (int b = 0; b < nb && nt < MAXTILES; b++) {
                w[WS_TILE_E / 4 + nt] = e;
                w[WS_TILE_R / 4 + nt] = off + b * BM;
                nt++;
            }
            off += nb * BM;
        }
        w[WS_NTILES / 4] = nt;
    }
    for (int i = threadIdx.x; i < RMAX; i += 64) w[WS_ROW_TOK / 4 + i] = -1;
}

// ---------------- scatter ----------------
__global__ __launch_bounds__(256) void k_scatter(int* __restrict__ w,
                                                 float* __restrict__ wf) {
    int t = blockIdx.x * 256 + threadIdx.x;
    if (t >= T_TOK) return;
#pragma unroll
    for (int k = 0; k < 2; k++) {
        int e   = w[WS_TOK_E / 4 + 2 * t + k];
        int pos = atomicAdd(&w[WS_CURSOR / 4 + e], 1);
        if (pos < RMAX) {
            w[WS_ROW_TOK / 4 + pos] = t;
            wf[WS_ROW_W / 4 + pos]  = wf[WS_TOK_W / 4 + 2 * t + k];
        }
    }
}

// pack 8 fp32 -> 8 bf16 (16 B)
__device__ inline uint4 pack8(float4 a, float4 b) {
    union { bf16 h[8]; uint4 u; } pk;
    pk.h[0] = (bf16)a.x; pk.h[1] = (bf16)a.y; pk.h[2] = (bf16)a.z; pk.h[3] = (bf16)a.w;
    pk.h[4] = (bf16)b.x; pk.h[5] = (bf16)b.y; pk.h[6] = (bf16)b.z; pk.h[7] = (bf16)b.w;
    return pk.u;
}
__device__ inline uint32_t pack2(float a, float b) {
    union { bf16 h[2]; uint32_t u; } pk;
    pk.h[0] = (bf16)a; pk.h[1] = (bf16)b;
    return pk.u;
}

// ---------------- FFN1: H[:, h0:h0+CW] = relu(gather(xs) @ W1[e] + b1[e]) ----
__global__ __launch_bounds__(256) void k_ffn1(const float* __restrict__ xs,
                                              const float* __restrict__ W1,
                                              const float* __restrict__ b1,
                                              const int* __restrict__ wsi,
                                              bf16* __restrict__ H,
                                              int h0, int CW) {
    int ntiles = wsi[WS_NTILES / 4];
    int tile = blockIdx.y;
    if (tile >= ntiles) return;
    int e    = wsi[WS_TILE_E / 4 + tile];
    int row0 = wsi[WS_TILE_R / 4 + tile];
    int n0l  = blockIdx.x * BN;
    int n0g  = h0 + n0l;

    const int*   row_tok = wsi + WS_ROW_TOK / 4;
    const float* Be      = W1 + (size_t)e * IDIM * HID;
    const float* bias_e  = b1 + (size_t)e * HID;

    __shared__ bf16 sA[BM * BK];      // [row][k], stride 64
    __shared__ bf16 sB[BN * 72];      // [n][k^swz], stride 72

    int t    = threadIdx.x;
    int lane = t & 63, wv = t >> 6;
    int wx = wv & 1, wy = wv >> 1;
    int lm = lane & 15, q = lane >> 4;

    int rtk[4];
#pragma unroll
    for (int i = 0; i < 4; i++) rtk[i] = row_tok[row0 + (t >> 3) + i * 32];

    f32x4 acc[4][4];
#pragma unroll
    for (int i = 0; i < 4; i++)
#pragma unroll
        for (int j = 0; j < 4; j++) acc[i][j] = (f32x4){0.f, 0.f, 0.f, 0.f};

    for (int kc = 0; kc < IDIM / BK; kc++) {
        if (kc) __syncthreads();
        // stage A (gathered, fp32 -> bf16)
#pragma unroll
        for (int i = 0; i < 4; i++) {
            int u = t + i * 256;
            int row = u >> 3, k8 = (u & 7) * 8;
            uint4 v;
            if (rtk[i] >= 0) {
                const float* g = xs + (size_t)rtk[i] * IDIM + kc * BK + k8;
                v = pack8(*(const float4*)g, *(const float4*)(g + 4));
            } else v = make_uint4(0u, 0u, 0u, 0u);
            *(uint4*)&sA[row * BK + k8] = v;
        }
        // stage B transposed (fp32 -> bf16, k-swizzled)
#pragma unroll
        for (int i = 0; i < 2; i++) {
            int u = t + i * 256;
            int noct = u & 15, kp = u >> 4;
            int k = kp * 2;
            const float* g = Be + (size_t)(kc * BK + k) * HID + n0g + noct * 8;
            float4 r0a = *(const float4*)g;
            float4 r0b = *(const float4*)(g + 4);
            float4 r1a = *(const float4*)(g + HID);
            float4 r1b = *(const float4*)(g + HID + 4);
            float a0[8] = {r0a.x, r0a.y, r0a.z, r0a.w, r0b.x, r0b.y, r0b.z, r0b.w};
            float a1[8] = {r1a.x, r1a.y, r1a.z, r1a.w, r1b.x, r1b.y, r1b.z, r1b.w};
            int kswz = k ^ ((noct & 3) * 16);
            int hwb  = noct * 8 * 72 + kswz;
#pragma unroll
            for (int j = 0; j < 8; j++)
                *(uint32_t*)&sB[hwb + j * 72] = pack2(a0[j], a1[j]);
        }
        __syncthreads();
#pragma unroll
        for (int ks = 0; ks < 2; ks++) {
            bf16x8 aF[4], bF[4];
#pragma unroll
            for (int mt = 0; mt < 4; mt++)
                aF[mt] = *(bf16x8*)&sA[(wy * 64 + mt * 16 + lm) * BK + ks * 32 + q * 8];
#pragma unroll
            for (int nt = 0; nt < 4; nt++) {
                int n  = wx * 64 + nt * 16 + lm;
                int kk = (ks * 32 + q * 8) ^ (((n >> 3) & 3) * 16);
                bF[nt] = *(bf16x8*)&sB[n * 72 + kk];
            }
#pragma unroll
            for (int mt = 0; mt < 4; mt++)
#pragma unroll
                for (int nt = 0; nt < 4; nt++)
                    acc[mt][nt] = __builtin_amdgcn_mfma_f32_16x16x32_bf16(
                        aF[mt], bF[nt], acc[mt][nt], 0, 0, 0);
        }
    }

#pragma unroll
    for (int nt = 0; nt < 4; nt++) {
        int col_l = n0l + wx * 64 + nt * 16 + lm;
        float bv  = bias_e[h0 + col_l];
#pragma unroll
        for (int mt = 0; mt < 4; mt++) {
            int rloc = wy * 64 + mt * 16 + q * 4;
#pragma unroll
            for (int r = 0; r < 4; r++) {
                float v = fmaxf(acc[mt][nt][r] + bv, 0.f);
                H[(size_t)(row0 + rloc + r) * CW + col_l] = (bf16)v;
            }
        }
    }
}

// ---------------- FFN2: out[tok] += w * (H @ W2[e][h0:,:] + b2[e]) ---------
__global__ __launch_bounds__(256) void k_ffn2(const bf16* __restrict__ H,
                                              const float* __restrict__ W2,
                                              const float* __restrict__ b2,
                                              const int* __restrict__ wsi,
                                              const float* __restrict__ wsf,
                                              float* __restrict__ out,
                                              int h0, int CW, int addb) {
    int ntiles = wsi[WS_NTILES / 4];
    int tile = blockIdx.y;
    if (tile >= ntiles) return;
    int e    = wsi[WS_TILE_E / 4 + tile];
    int row0 = wsi[WS_TILE_R / 4 + tile];
    int n0   = blockIdx.x * BN;

    const int*   row_tok = wsi + WS_ROW_TOK / 4;
    const float* row_w   = wsf + WS_ROW_W / 4;
    const float* Be      = W2 + (size_t)e * HID * IDIM;
    const float* bias_e  = b2 + (size_t)e * IDIM;

    __shared__ bf16 sA[BM * BK];
    __shared__ bf16 sB[BN * 72];

    int t    = threadIdx.x;
    int lane = t & 63, wv = t >> 6;
    int wx = wv & 1, wy = wv >> 1;
    int lm = lane & 15, q = lane >> 4;

    f32x4 acc[4][4];
#pragma unroll
    for (int i = 0; i < 4; i++)
#pragma unroll
        for (int j = 0; j < 4; j++) acc[i][j] = (f32x4){0.f, 0.f, 0.f, 0.f};

    int kiters = CW / BK;
    for (int kc = 0; kc < kiters; kc++) {
        if (kc) __syncthreads();
        // stage A from H (already bf16)
#pragma unroll
        for (int i = 0; i < 4; i++) {
            int u = t + i * 256;
            int row = u >> 3, k8 = (u & 7) * 8;
            *(uint4*)&sA[row * BK + k8] =
                *(const uint4*)&H[(size_t)(row0 + row) * CW + kc * BK + k8];
        }
        // stage B transposed (fp32 -> bf16)
#pragma unroll
        for (int i = 0; i < 2; i++) {
            int u = t + i * 256;
            int noct = u & 15, kp = u >> 4;
            int k = kp * 2;
            const float* g = Be + (size_t)(h0 + kc * BK + k) * IDIM + n0 + noct * 8;
            float4 r0a = *(const float4*)g;
            float4 r0b = *(const float4*)(g + 4);
            float4 r1a = *(const float4*)(g + IDIM);
            float4 r1b = *(const float4*)(g + IDIM + 4);
            float a0[8] = {r0a.x, r0a.y, r0a.z, r0a.w, r0b.x, r0b.y, r0b.z, r0b.w};
            float a1[8] = {r1a.x, r1a.y, r1a.z, r1a.w, r1b.x, r1b.y, r1b.z, r1b.w};
            int kswz = k ^ ((noct & 3) * 16);
            int hwb  = noct * 8 * 72 + kswz;
#pragma unroll
            for (int j = 0; j < 8; j++)
                *(uint32_t*)&sB[hwb + j * 72] = pack2(a0[j], a1[j]);
        }
        __syncthreads();
#pragma unroll
        for (int ks = 0; ks < 2; ks++) {
            bf16x8 aF[4], bF[4];
#pragma unroll
            for (int mt = 0; mt < 4; mt++)
                aF[mt] = *(bf16x8*)&sA[(wy * 64 + mt * 16 + lm) * BK + ks * 32 + q * 8];
#pragma unroll
            for (int nt = 0; nt < 4; nt++) {
                int n  = wx * 64 + nt * 16 + lm;
                int kk = (ks * 32 + q * 8) ^ (((n >> 3) & 3) * 16);
                bF[nt] = *(bf16x8*)&sB[n * 72 + kk];
            }
#pragma unroll
            for (int mt = 0; mt < 4; mt++)
#pragma unroll
                for (int nt = 0; nt < 4; nt++)
                    acc[mt][nt] = __builtin_amdgcn_mfma_f32_16x16x32_bf16(
                        aF[mt], bF[nt], acc[mt][nt], 0, 0, 0);
        }
    }

    // epilogue: weighted atomic add into fp32 out (exactly 2 adds/element)
    int   tokr[16];
    float wr[16];
#pragma unroll
    for (int mt = 0; mt < 4; mt++)
#pragma unroll
        for (int r = 0; r < 4; r++) {
            int rg = row0 + wy * 64 + mt * 16 + q * 4 + r;
            tokr[mt * 4 + r] = row_tok[rg];
            wr[mt * 4 + r]   = row_w[rg];
        }
#pragma unroll
    for (int nt = 0; nt < 4; nt++) {
        int col  = n0 + wx * 64 + nt * 16 + lm;
        float bv = addb ? bias_e[col] : 0.f;
#pragma unroll
        for (int mt = 0; mt < 4; mt++)
#pragma unroll
            for (int r = 0; r < 4; r++) {
                int tok = tokr[mt * 4 + r];
                if (tok >= 0)
                    atomicAdd(&out[(size_t)tok * IDIM + col],
                              wr[mt * 4 + r] * (acc[mt][nt][r] + bv));
            }
    }
}

// ---------------- zero-workspace fallback (fp32) ----------------
__global__ __launch_bounds__(256) void k_fallback(const float* __restrict__ xs,
                                                  const float* __restrict__ Wg,
                                                  const float* __restrict__ W1,
                                                  const float* __restrict__ b1,
                                                  const float* __restrict__ W2,
                                                  const float* __restrict__ b2,
                                                  float* __restrict__ out) {
    __shared__ float xbuf[IDIM];
    __shared__ float hbuf[256];
    __shared__ float slog[NE];
    __shared__ int   sel[2];
    __shared__ float selw[2];

    int t   = blockIdx.x;
    int tid = threadIdx.x;

    for (int i = tid; i < IDIM; i += 256)
        xbuf[i] = xs[(size_t)t * IDIM + i];
    __syncthreads();
    {
        int e = tid >> 5, l = tid & 31;
        float p = 0.f;
        for (int d = l; d < IDIM; d += 32)
            p += xbuf[d] * Wg[e * IDIM + d];
        for (int off = 16; off > 0; off >>= 1) p += __shfl_down(p, off, 32);
        if (l == 0) slog[e] = p;
    }
    __syncthreads();
    if (tid == 0) {
        int e0 = 0; float l0 = slog[0];
        for (int e = 1; e < NE; e++) if (slog[e] > l0) { l0 = slog[e]; e0 = e; }
        int e1 = -1; float l1 = -1e30f;
        for (int e = 0; e < NE; e++) if (e != e0 && slog[e] > l1) { l1 = slog[e]; e1 = e; }
        if (e1 < 0) e1 = (e0 + 1) & 7;
        float z = __expf(l1 - l0);
        sel[0] = e0; sel[1] = e1;
        selw[0] = 1.f / (1.f + z);
        selw[1] = z / (1.f + z);
    }
    __syncthreads();

    float ytot[4] = {0.f, 0.f, 0.f, 0.f};
#pragma unroll
    for (int s = 0; s < 2; s++) {
        int   e = sel[s];
        float w = selw[s];
        const float* W1e = W1 + (size_t)e * IDIM * HID;
        const float* W2e = W2 + (size_t)e * HID * IDIM;
        float ys[4] = {0.f, 0.f, 0.f, 0.f};
        for (int hb = 0; hb < HID / 256; hb++) {
            int h = hb * 256 + tid;
            float acc = b1[e * HID + h];
            for (int d = 0; d < IDIM; d++)
                acc += xbuf[d] * W1e[(size_t)d * HID + h];
            __syncthreads();
            hbuf[tid] = fmaxf(acc, 0.f);
            __syncthreads();
            for (int hh = 0; hh < 256; hh++) {
                float hv = hbuf[hh];
                const float* wrow = W2e + (size_t)(hb * 256 + hh) * IDIM;
#pragma unroll
                for (int cc = 0; cc < 4; cc++)
                    ys[cc] += hv * wrow[cc * 256 + tid];
            }
        }
#pragma unroll
        for (int cc = 0; cc < 4; cc++)
            ytot[cc] += w * (ys[cc] + b2[e * IDIM + cc * 256 + tid]);
    }
#pragma unroll
    for (int cc = 0; cc < 4; cc++)
        out[(size_t)t * IDIM + cc * 256 + tid] = ytot[cc];
}

extern "C" void kernel_launch(void* const* d_in, const int* in_sizes, int n_in,
                              void* d_out, int out_size, void* d_ws, size_t ws_size,
                              hipStream_t stream) {
    int o = (n_in >= 7 && in_sizes[1] == 1) ? 1 : 0;
    const float* xs = (const float*)d_in[0];
    const float* Wg = (const float*)d_in[1 + o];
    const float* W1 = (const float*)d_in[2 + o];
    const float* b1 = (const float*)d_in[3 + o];
    const float* W2 = (const float*)d_in[4 + o];
    const float* b2 = (const float*)d_in[5 + o];
    float* out = (float*)d_out;

    if (ws_size < WS_MIN_FAST || d_ws == nullptr) {
        k_fallback<<<T_TOK, 256, 0, stream>>>(xs, Wg, W1, b1, W2, b2, out);
        return;
    }

    char*  ws  = (char*)d_ws;
    int*   wsi = (int*)d_ws;
    float* wsf = (float*)d_ws;
    bf16*  H   = (bf16*)(ws + WS_H);

    int HC = 1;
    while (HC < 32 &&
           (size_t)WS_H + (size_t)RMAX * (HID / HC) * 2 > ws_size)
        HC <<= 1;
    int CW = HID / HC;

    k_zero_meta<<<1, 64, 0, stream>>>(wsi);
    k_zero_out<<<T_TOK, 256, 0, stream>>>((float4*)out);

    k_router<<<T_TOK / 4, 256, 0, stream>>>(xs, Wg, wsi + WS_COUNTS / 4,
                                            wsi + WS_TOK_E / 4, wsf + WS_TOK_W / 4);
    k_plan<<<1, 64, 0, stream>>>(wsi);
    k_scatter<<<T_TOK / 256, 256, 0, stream>>>(wsi, wsf);

    for (int c = 0; c < HC; c++) {
        k_ffn1<<<dim3(CW / BN, MAXTILES), 256, 0, stream>>>(
            xs, W1, b1, wsi, H, c * CW, CW);
        k_ffn2<<<dim3(IDIM / BN, MAXTILES), 256, 0, stream>>>(
            H, W2, b2, wsi, wsf, out, c * CW, CW, c == 0 ? 1 : 0);
    }
}

// Round 6
// 519.826 us; speedup vs baseline: 1.0878x; 1.0878x over previous
//
#include <hip/hip_runtime.h>
#include <hip/hip_bf16.h>
#include <stdint.h>

#define T_TOK 2048
#define IDIM  1024
#define HID   4096
#define NE    8
#define BM    128
#define BN    128
#define BK    64
#define RMAX  5120
#define MAXTILES 40

typedef __bf16 bf16;
typedef bf16  bf16x8 __attribute__((ext_vector_type(8)));
typedef float f32x4  __attribute__((ext_vector_type(4)));

// ---- workspace layout (byte offsets) ----
#define WS_NTILES   128      // 1 int
#define WS_TILE_E   192      // 64 int
#define WS_TILE_R   448      // 64 int
#define WS_TOK_E    1024     // 2*T int
#define WS_TOK_W    17408    // 2*T float
#define WS_ROW_TOK  33792    // RMAX int (-1 = pad)
#define WS_ROW_W    54272    // RMAX float
#define WS_H        131072   // RMAX * (HID/HC) bf16
#define WS_MIN_FAST ((size_t)WS_H + (size_t)RMAX * (HID / 32) * 2)  // ~1.44 MB

// ---------------- zero out (ffn2 accumulates into it atomically) ----------
__global__ __launch_bounds__(256) void k_zero_out(float4* __restrict__ a) {
    a[blockIdx.x * 256 + threadIdx.x] = make_float4(0.f, 0.f, 0.f, 0.f);
}

// ---------------- router: one wave per token (pure fp32, no atomics) ------
__global__ __launch_bounds__(256) void k_router(const float* __restrict__ xs,
                                                const float* __restrict__ Wg,
                                                int* __restrict__ tok_e,
                                                float* __restrict__ tok_w) {
    __shared__ float sWg[NE * IDIM];
    for (int i = threadIdx.x; i < NE * IDIM; i += 256) sWg[i] = Wg[i];
    __syncthreads();
    int wave = threadIdx.x >> 6, lane = threadIdx.x & 63;
    int t = blockIdx.x * 4 + wave;
    if (t >= T_TOK) return;
    float p[NE];
#pragma unroll
    for (int e = 0; e < NE; e++) p[e] = 0.f;
    for (int j = 0; j < IDIM / 64; j++) {
        float x = xs[(size_t)t * IDIM + j * 64 + lane];
#pragma unroll
        for (int e = 0; e < NE; e++)
            p[e] += x * sWg[e * IDIM + j * 64 + lane];
    }
#pragma unroll
    for (int e = 0; e < NE; e++) {
        float v = p[e];
        for (int off = 32; off > 0; off >>= 1) v += __shfl_down(v, off);
        p[e] = v;
    }
    if (lane == 0) {
        int e0 = 0; float l0 = p[0];
        for (int e = 1; e < NE; e++) if (p[e] > l0) { l0 = p[e]; e0 = e; }
        int e1 = -1; float l1 = -1e30f;
        for (int e = 0; e < NE; e++) if (e != e0 && p[e] > l1) { l1 = p[e]; e1 = e; }
        if (e1 < 0) e1 = (e0 + 1) & 7;
        float z = __expf(l1 - l0);              // <= 1
        tok_e[2 * t]     = e0;  tok_e[2 * t + 1] = e1;
        tok_w[2 * t]     = 1.f / (1.f + z);
        tok_w[2 * t + 1] = z / (1.f + z);
    }
}

// ---------------- setup: count + plan + scatter, one block -----------------
__global__ __launch_bounds__(256) void k_setup(int* __restrict__ w,
                                               float* __restrict__ wf) {
    __shared__ int cnt[NE];
    __shared__ int cur[NE];
    int tid = threadIdx.x;
    if (tid < NE) cnt[tid] = 0;
    for (int i = tid; i < RMAX; i += 256) w[WS_ROW_TOK / 4 + i] = -1;
    __syncthreads();
    for (int i = tid; i < 2 * T_TOK; i += 256)
        atomicAdd(&cnt[w[WS_TOK_E / 4 + i]], 1);
    __syncthreads();
    if (tid == 0) {
        int off = 0, nt = 0;
        for (int e = 0; e < NE; e++) {
            cur[e] = off;
            int nb = (cnt[e] + BM - 1) / BM;
            for (int b = 0; b < nb && nt < MAXTILES; b++) {
                w[WS_TILE_E / 4 + nt] = e;
                w[WS_TILE_R / 4 + nt] = off + b * BM;
                nt++;
            }
            off += nb * BM;
        }
        w[WS_NTILES / 4] = nt;
    }
    __syncthreads();
    for (int i = tid; i < 2 * T_TOK; i += 256) {
        int e   = w[WS_TOK_E / 4 + i];
        int pos = atomicAdd(&cur[e], 1);
        if (pos < RMAX) {
            w[WS_ROW_TOK / 4 + pos] = i >> 1;
            wf[WS_ROW_W / 4 + pos]  = wf[WS_TOK_W / 4 + i];
        }
    }
}

// pack 8 fp32 -> 8 bf16 (16 B)
__device__ inline uint4 pack8(float4 a, float4 b) {
    union { bf16 h[8]; uint4 u; } pk;
    pk.h[0] = (bf16)a.x; pk.h[1] = (bf16)a.y; pk.h[2] = (bf16)a.z; pk.h[3] = (bf16)a.w;
    pk.h[4] = (bf16)b.x; pk.h[5] = (bf16)b.y; pk.h[6] = (bf16)b.z; pk.h[7] = (bf16)b.w;
    return pk.u;
}
__device__ inline uint32_t pack2(float a, float b) {
    union { bf16 h[2]; uint32_t u; } pk;
    pk.h[0] = (bf16)a; pk.h[1] = (bf16)b;
    return pk.u;
}

// ---------------- FFN1: H[:, h0:h0+CW] = relu(gather(xs) @ W1[e] + b1[e]) ----
__global__ __launch_bounds__(256) void k_ffn1(const float* __restrict__ xs,
                                              const float* __restrict__ W1,
                                              const float* __restrict__ b1,
                                              const int* __restrict__ wsi,
                                              bf16* __restrict__ H,
                                              int h0, int CW) {
    int ntiles = wsi[WS_NTILES / 4];
    int tile = blockIdx.y;
    if (tile >= ntiles) return;
    int e    = wsi[WS_TILE_E / 4 + tile];
    int row0 = wsi[WS_TILE_R / 4 + tile];
    int n0l  = blockIdx.x * BN;
    int n0g  = h0 + n0l;

    const int*   row_tok = wsi + WS_ROW_TOK / 4;
    const float* Be      = W1 + (size_t)e * IDIM * HID;
    const float* bias_e  = b1 + (size_t)e * HID;

    __shared__ bf16 sA[BM * BK];      // [row][k], stride 64
    __shared__ bf16 sB[BN * 72];      // [n][k^swz], stride 72

    int t    = threadIdx.x;
    int lane = t & 63, wv = t >> 6;
    int wx = wv & 1, wy = wv >> 1;
    int lm = lane & 15, q = lane >> 4;

    int rtk[4];
#pragma unroll
    for (int i = 0; i < 4; i++) rtk[i] = row_tok[row0 + (t >> 3) + i * 32];

    f32x4 acc[4][4];
#pragma unroll
    for (int i = 0; i < 4; i++)
#pragma unroll
        for (int j = 0; j < 4; j++) acc[i][j] = (f32x4){0.f, 0.f, 0.f, 0.f};

    for (int kc = 0; kc < IDIM / BK; kc++) {
        if (kc) __syncthreads();
#pragma unroll
        for (int i = 0; i < 4; i++) {
            int u = t + i * 256;
            int row = u >> 3, k8 = (u & 7) * 8;
            uint4 v;
            if (rtk[i] >= 0) {
                const float* g = xs + (size_t)rtk[i] * IDIM + kc * BK + k8;
                v = pack8(*(const float4*)g, *(const float4*)(g + 4));
            } else v = make_uint4(0u, 0u, 0u, 0u);
            *(uint4*)&sA[row * BK + k8] = v;
        }
#pragma unroll
        for (int i = 0; i < 2; i++) {
            int u = t + i * 256;
            int noct = u & 15, kp = u >> 4;
            int k = kp * 2;
            const float* g = Be + (size_t)(kc * BK + k) * HID + n0g + noct * 8;
            float4 r0a = *(const float4*)g;
            float4 r0b = *(const float4*)(g + 4);
            float4 r1a = *(const float4*)(g + HID);
            float4 r1b = *(const float4*)(g + HID + 4);
            float a0[8] = {r0a.x, r0a.y, r0a.z, r0a.w, r0b.x, r0b.y, r0b.z, r0b.w};
            float a1[8] = {r1a.x, r1a.y, r1a.z, r1a.w, r1b.x, r1b.y, r1b.z, r1b.w};
            int kswz = k ^ ((noct & 3) * 16);
            int hwb  = noct * 8 * 72 + kswz;
#pragma unroll
            for (int j = 0; j < 8; j++)
                *(uint32_t*)&sB[hwb + j * 72] = pack2(a0[j], a1[j]);
        }
        __syncthreads();
#pragma unroll
        for (int ks = 0; ks < 2; ks++) {
            bf16x8 aF[4], bF[4];
#pragma unroll
            for (int mt = 0; mt < 4; mt++)
                aF[mt] = *(bf16x8*)&sA[(wy * 64 + mt * 16 + lm) * BK + ks * 32 + q * 8];
#pragma unroll
            for (int nt = 0; nt < 4; nt++) {
                int n  = wx * 64 + nt * 16 + lm;
                int kk = (ks * 32 + q * 8) ^ (((n >> 3) & 3) * 16);
                bF[nt] = *(bf16x8*)&sB[n * 72 + kk];
            }
#pragma unroll
            for (int mt = 0; mt < 4; mt++)
#pragma unroll
                for (int nt = 0; nt < 4; nt++)
                    acc[mt][nt] = __builtin_amdgcn_mfma_f32_16x16x32_bf16(
                        aF[mt], bF[nt], acc[mt][nt], 0, 0, 0);
        }
    }

#pragma unroll
    for (int nt = 0; nt < 4; nt++) {
        int col_l = n0l + wx * 64 + nt * 16 + lm;
        float bv  = bias_e[h0 + col_l];
#pragma unroll
        for (int mt = 0; mt < 4; mt++) {
            int rloc = wy * 64 + mt * 16 + q * 4;
#pragma unroll
            for (int r = 0; r < 4; r++) {
                float v = fmaxf(acc[mt][nt][r] + bv, 0.f);
                H[(size_t)(row0 + rloc + r) * CW + col_l] = (bf16)v;
            }
        }
    }
}

// -------- FFN2 (split-K over blockIdx.z): out[tok] += w*(H@W2 + b2) --------
__global__ __launch_bounds__(256) void k_ffn2(const bf16* __restrict__ H,
                                              const float* __restrict__ W2,
                                              const float* __restrict__ b2,
                                              const int* __restrict__ wsi,
                                              const float* __restrict__ wsf,
                                              float* __restrict__ out,
                                              int h0, int CW, int addb) {
    int ntiles = wsi[WS_NTILES / 4];
    int tile = blockIdx.y;
    if (tile >= ntiles) return;
    int e    = wsi[WS_TILE_E / 4 + tile];
    int row0 = wsi[WS_TILE_R / 4 + tile];
    int n0   = blockIdx.x * BN;
    int kw   = CW / gridDim.z;            // K width per z-slice
    int kb   = blockIdx.z * kw;           // K base within this CW chunk

    const int*   row_tok = wsi + WS_ROW_TOK / 4;
    const float* row_w   = wsf + WS_ROW_W / 4;
    const float* Be      = W2 + (size_t)e * HID * IDIM;
    const float* bias_e  = b2 + (size_t)e * IDIM;

    __shared__ bf16 sA[BM * BK];
    __shared__ bf16 sB[BN * 72];

    int t    = threadIdx.x;
    int lane = t & 63, wv = t >> 6;
    int wx = wv & 1, wy = wv >> 1;
    int lm = lane & 15, q = lane >> 4;

    f32x4 acc[4][4];
#pragma unroll
    for (int i = 0; i < 4; i++)
#pragma unroll
        for (int j = 0; j < 4; j++) acc[i][j] = (f32x4){0.f, 0.f, 0.f, 0.f};

    int kiters = kw / BK;
    for (int kc = 0; kc < kiters; kc++) {
        if (kc) __syncthreads();
#pragma unroll
        for (int i = 0; i < 4; i++) {
            int u = t + i * 256;
            int row = u >> 3, k8 = (u & 7) * 8;
            *(uint4*)&sA[row * BK + k8] =
                *(const uint4*)&H[(size_t)(row0 + row) * CW + kb + kc * BK + k8];
        }
#pragma unroll
        for (int i = 0; i < 2; i++) {
            int u = t + i * 256;
            int noct = u & 15, kp = u >> 4;
            int k = kp * 2;
            const float* g = Be + (size_t)(h0 + kb + kc * BK + k) * IDIM + n0 + noct * 8;
            float4 r0a = *(const float4*)g;
            float4 r0b = *(const float4*)(g + 4);
            float4 r1a = *(const float4*)(g + IDIM);
            float4 r1b = *(const float4*)(g + IDIM + 4);
            float a0[8] = {r0a.x, r0a.y, r0a.z, r0a.w, r0b.x, r0b.y, r0b.z, r0b.w};
            float a1[8] = {r1a.x, r1a.y, r1a.z, r1a.w, r1b.x, r1b.y, r1b.z, r1b.w};
            int kswz = k ^ ((noct & 3) * 16);
            int hwb  = noct * 8 * 72 + kswz;
#pragma unroll
            for (int j = 0; j < 8; j++)
                *(uint32_t*)&sB[hwb + j * 72] = pack2(a0[j], a1[j]);
        }
        __syncthreads();
#pragma unroll
        for (int ks = 0; ks < 2; ks++) {
            bf16x8 aF[4], bF[4];
#pragma unroll
            for (int mt = 0; mt < 4; mt++)
                aF[mt] = *(bf16x8*)&sA[(wy * 64 + mt * 16 + lm) * BK + ks * 32 + q * 8];
#pragma unroll
            for (int nt = 0; nt < 4; nt++) {
                int n  = wx * 64 + nt * 16 + lm;
                int kk = (ks * 32 + q * 8) ^ (((n >> 3) & 3) * 16);
                bF[nt] = *(bf16x8*)&sB[n * 72 + kk];
            }
#pragma unroll
            for (int mt = 0; mt < 4; mt++)
#pragma unroll
                for (int nt = 0; nt < 4; nt++)
                    acc[mt][nt] = __builtin_amdgcn_mfma_f32_16x16x32_bf16(
                        aF[mt], bF[nt], acc[mt][nt], 0, 0, 0);
        }
    }

    // epilogue: weighted atomic add (bias only from z==0 of chunk 0)
    int   tokr[16];
    float wr[16];
#pragma unroll
    for (int mt = 0; mt < 4; mt++)
#pragma unroll
        for (int r = 0; r < 4; r++) {
            int rg = row0 + wy * 64 + mt * 16 + q * 4 + r;
            tokr[mt * 4 + r] = row_tok[rg];
            wr[mt * 4 + r]   = row_w[rg];
        }
    int dobias = addb && (blockIdx.z == 0);
#pragma unroll
    for (int nt = 0; nt < 4; nt++) {
        int col  = n0 + wx * 64 + nt * 16 + lm;
        float bv = dobias ? bias_e[col] : 0.f;
#pragma unroll
        for (int mt = 0; mt < 4; mt++)
#pragma unroll
            for (int r = 0; r < 4; r++) {
                int tok = tokr[mt * 4 + r];
                if (tok >= 0)
                    atomicAdd(&out[(size_t)tok * IDIM + col],
                              wr[mt * 4 + r] * (acc[mt][nt][r] + bv));
            }
    }
}

// ---------------- zero-workspace fallback (fp32) ----------------
__global__ __launch_bounds__(256) void k_fallback(const float* __restrict__ xs,
                                                  const float* __restrict__ Wg,
                                                  const float* __restrict__ W1,
                                                  const float* __restrict__ b1,
                                                  const float* __restrict__ W2,
                                                  const float* __restrict__ b2,
                                                  float* __restrict__ out) {
    __shared__ float xbuf[IDIM];
    __shared__ float hbuf[256];
    __shared__ float slog[NE];
    __shared__ int   sel[2];
    __shared__ float selw[2];

    int t   = blockIdx.x;
    int tid = threadIdx.x;

    for (int i = tid; i < IDIM; i += 256)
        xbuf[i] = xs[(size_t)t * IDIM + i];
    __syncthreads();
    {
        int e = tid >> 5, l = tid & 31;
        float p = 0.f;
        for (int d = l; d < IDIM; d += 32)
            p += xbuf[d] * Wg[e * IDIM + d];
        for (int off = 16; off > 0; off >>= 1) p += __shfl_down(p, off, 32);
        if (l == 0) slog[e] = p;
    }
    __syncthreads();
    if (tid == 0) {
        int e0 = 0; float l0 = slog[0];
        for (int e = 1; e < NE; e++) if (slog[e] > l0) { l0 = slog[e]; e0 = e; }
        int e1 = -1; float l1 = -1e30f;
        for (int e = 0; e < NE; e++) if (e != e0 && slog[e] > l1) { l1 = slog[e]; e1 = e; }
        if (e1 < 0) e1 = (e0 + 1) & 7;
        float z = __expf(l1 - l0);
        sel[0] = e0; sel[1] = e1;
        selw[0] = 1.f / (1.f + z);
        selw[1] = z / (1.f + z);
    }
    __syncthreads();

    float ytot[4] = {0.f, 0.f, 0.f, 0.f};
#pragma unroll
    for (int s = 0; s < 2; s++) {
        int   e = sel[s];
        float w = selw[s];
        const float* W1e = W1 + (size_t)e * IDIM * HID;
        const float* W2e = W2 + (size_t)e * HID * IDIM;
        float ys[4] = {0.f, 0.f, 0.f, 0.f};
        for (int hb = 0; hb < HID / 256; hb++) {
            int h = hb * 256 + tid;
            float acc = b1[e * HID + h];
            for (int d = 0; d < IDIM; d++)
                acc += xbuf[d] * W1e[(size_t)d * HID + h];
            __syncthreads();
            hbuf[tid] = fmaxf(acc, 0.f);
            __syncthreads();
            for (int hh = 0; hh < 256; hh++) {
                float hv = hbuf[hh];
                const float* wrow = W2e + (size_t)(hb * 256 + hh) * IDIM;
#pragma unroll
                for (int cc = 0; cc < 4; cc++)
                    ys[cc] += hv * wrow[cc * 256 + tid];
            }
        }
#pragma unroll
        for (int cc = 0; cc < 4; cc++)
            ytot[cc] += w * (ys[cc] + b2[e * IDIM + cc * 256 + tid]);
    }
#pragma unroll
    for (int cc = 0; cc < 4; cc++)
        out[(size_t)t * IDIM + cc * 256 + tid] = ytot[cc];
}

extern "C" void kernel_launch(void* const* d_in, const int* in_sizes, int n_in,
                              void* d_out, int out_size, void* d_ws, size_t ws_size,
                              hipStream_t stream) {
    int o = (n_in >= 7 && in_sizes[1] == 1) ? 1 : 0;
    const float* xs = (const float*)d_in[0];
    const float* Wg = (const float*)d_in[1 + o];
    const float* W1 = (const float*)d_in[2 + o];
    const float* b1 = (const float*)d_in[3 + o];
    const float* W2 = (const float*)d_in[4 + o];
    const float* b2 = (const float*)d_in[5 + o];
    float* out = (float*)d_out;

    if (ws_size < WS_MIN_FAST || d_ws == nullptr) {
        k_fallback<<<T_TOK, 256, 0, stream>>>(xs, Wg, W1, b1, W2, b2, out);
        return;
    }

    char*  ws  = (char*)d_ws;
    int*   wsi = (int*)d_ws;
    float* wsf = (float*)d_ws;
    bf16*  H   = (bf16*)(ws + WS_H);

    int HC = 1;
    while (HC < 32 &&
           (size_t)WS_H + (size_t)RMAX * (HID / HC) * 2 > ws_size)
        HC <<= 1;
    int CW = HID / HC;
    int SK = 4;                            // split-K for ffn2
    while (CW / SK < BK) SK >>= 1;

    k_zero_out<<<T_TOK, 256, 0, stream>>>((float4*)out);
    k_router<<<T_TOK / 4, 256, 0, stream>>>(xs, Wg, wsi + WS_TOK_E / 4,
                                            wsf + WS_TOK_W / 4);
    k_setup<<<1, 256, 0, stream>>>(wsi, wsf);

    for (int c = 0; c < HC; c++) {
        k_ffn1<<<dim3(CW / BN, MAXTILES), 256, 0, stream>>>(
            xs, W1, b1, wsi, H, c * CW, CW);
        k_ffn2<<<dim3(IDIM / BN, MAXTILES, SK), 256, 0, stream>>>(
            H, W2, b2, wsi, wsf, out, c * CW, CW, c == 0 ? 1 : 0);
    }
}